// Round 13
// baseline (176.759 us; speedup 1.0000x reference)
//
#include <hip/hip_runtime.h>
#include <cstdint>
#include <cmath>

#define B_ 4
#define H_ 256
#define C_ 80
#define TX_ 256
#define TY_ 1024
#define NEGF (-1e9f)

// output layout (floats): o_en_ex [B,H,TY] | logp [B,TX,TY] | attn [B,TX,TY] | dr [B,TX]
#define OFF_LOGP (B_*H_*TY_)
#define OFF_ATTN (OFF_LOGP + B_*TX_*TY_)
#define OFF_DR   (OFF_ATTN + B_*TX_*TY_)

// ---------------------------------------------------------------------------
// Kernel A (R18 build, validated ~15us warm via R24 duplicate-launch):
// logp, 4 waves/SIMD, math BIT-IDENTICAL.
// ---------------------------------------------------------------------------
__global__ __launch_bounds__(256) void k_logp(
    const float* __restrict__ mu, const float* __restrict__ ls,
    const float* __restrict__ y, const int* __restrict__ xlp,
    const int* __restrict__ ylp, float* __restrict__ logp_out,
    float* __restrict__ lpT)
{
  const int b  = blockIdx.z;
  const int tq = blockIdx.y;              // t-quarter: rows tq*256 .. tq*256+255
  const int x0 = blockIdx.x * 4;
  const int tid = threadIdx.x;
  const int lane = tid & 63;
  const int xi = tid >> 6;                // wave id == x-column index

  __shared__ double2 s_wm[4][C_];         // (w, -2*w*mu) packed -> ds_read_b128
  __shared__ double  s_wm2[4][C_];
  __shared__ double  s_lsv[4][C_];
  __shared__ double  s_K[4];
  __shared__ double  s_t0[4];
  __shared__ float   tile[256][4];        // [t_local][x] transpose staging

  for (int i = tid; i < 4 * C_; i += 256) {
    int xj = i / C_, c = i - xj * C_;
    double m = (double)mu[(b * C_ + c) * TX_ + x0 + xj];
    double l = (double)ls[(b * C_ + c) * TX_ + x0 + xj];
    double w = exp(-2.0 * l);
    s_wm[xj][c]  = make_double2(w, -2.0 * w * m);
    s_wm2[xj][c] = w * m * m;
    s_lsv[xj][c] = l;
  }
  __syncthreads();
  {
    int cc = lane;
    double kp = (cc < C_) ? s_wm2[xi][cc] : 0.0;
    double tp = (cc < C_) ? s_lsv[xi][cc] : 0.0;
    if (cc + 64 < C_) { kp += s_wm2[xi][cc + 64]; tp += s_lsv[xi][cc + 64]; }
#pragma unroll
    for (int off = 32; off; off >>= 1) {
      kp += __shfl_down(kp, off);
      tp += __shfl_down(tp, off);
    }
    if (cc == 0) { s_K[xi] = kp; s_t0[xi] = -0.5 * (tp * (1.0 / C_)); }
  }
  __syncthreads();

  double acc[4];
#pragma unroll
  for (int k = 0; k < 4; ++k) acc[k] = 0.0;

  const float4* yp = (const float4*)(y + (size_t)b * C_ * TY_ + tq * 256) + lane;
#pragma unroll 4
  for (int c = 0; c < C_; ++c) {
    float4 yv = yp[c * (TY_ / 4)];
    double y0 = yv.x, y1 = yv.y, y2 = yv.z, y3 = yv.w;
    double2 wm = s_wm[xi][c];
    double w = wm.x, m1 = wm.y;
    double u0 = fma(w, y0, m1), u1 = fma(w, y1, m1);
    double u2 = fma(w, y2, m1), u3 = fma(w, y3, m1);
    acc[0] = fma(u0, y0, acc[0]);
    acc[1] = fma(u1, y1, acc[1]);
    acc[2] = fma(u2, y2, acc[2]);
    acc[3] = fma(u3, y3, acc[3]);
  }

  const int xlen = xlp[b], ylen = ylp[b];
  const int x  = x0 + xi;
  const int t0 = tq * 256 + lane * 4;
  {
    double c0 = s_t0[xi], K = s_K[xi];
    float r[4];
#pragma unroll
    for (int k = 0; k < 4; ++k)
      r[k] = (float)((acc[k] + K) * (-0.5 / C_) + c0);
    *(float4*)&logp_out[((size_t)(b * TX_ + x)) * TY_ + t0] =
        make_float4(r[0], r[1], r[2], r[3]);
    bool xm = x < xlen;
#pragma unroll
    for (int k = 0; k < 4; ++k)
      tile[lane * 4 + k][xi] = (xm && (t0 + k) < ylen) ? r[k] : NEGF;
  }
  __syncthreads();

  float* dst = lpT + (size_t)b * TY_ * TX_ + x0;
  const float4* tp = (const float4*)tile;
  *(float4*)&dst[(size_t)(tq * 256 + tid) * TX_] = tp[tid];
}

// ---------------------------------------------------------------------------
// Kernel B (R26): R23 consumer (exact, best build 76.4us) + SEVEN producers.
//
// R25 post-mortem: two-consumer split null (boundary sync ate the halved
// VALU) -> reverted.  New accounting: consumer VALU issue ~35-45 cyc/step
// (confirmed by VALUBusy), DS pipe ~24, but producer staging at R14's
// measured ~6.7 B/cyc/wave x3 waves = ~51 cyc/step -- the staging rate,
// never the consumer, plausibly bounds every structure tried so far (all
// six nulls rearranged the consumer only).  This round: 512-thread block,
// 1 consumer + 7 producers (c strided mod 7) -> staging ~22 cyc/step.
// Slot-reuse gate (vprog >= c-6) is producer-count-independent: chunk c+6
// touches slot c%6 only after the consumer published chunk c.  flags are
// per-chunk; pair-poll tolerates out-of-order completion.  8 waves =
// 2/SIMD; consumer shares its SIMD with one mostly-VMEM-blocked producer.
// Consumer math/loop/backtrack byte-identical to R23.  dur[] init guarded
// (tid may exceed TX_ now).
// ---------------------------------------------------------------------------
#define POLL_PAIR(i)                                                     \
  { const volatile unsigned long long* vp2 =                             \
        (const volatile unsigned long long*)&flags[i];                   \
    for (;;) { unsigned long long fv = *vp2;                             \
      if ((unsigned)fv && (fv >> 32)) break;                             \
      __builtin_amdgcn_s_sleep(1); }                                     \
    asm volatile("" ::: "memory"); }

#define ISSUE8(BANK, SC, HALF)                                           \
  _Pragma("unroll")                                                      \
  for (int i = 0; i < 8; ++i)                                            \
    BANK[i] = ring4[(SC) * 1024 + ((HALF) * 8 + i) * 64 + lane];

#define CONS8(BANK)                                                      \
  _Pragma("unroll")                                                      \
  for (int u = 0; u < 8; ++u) {                                          \
    float4 col = BANK[u];                                                \
    sh_i = __builtin_amdgcn_update_dpp(sh_i, __float_as_int(v3),         \
                                       0x138, 0xf, 0xf, false);          \
    float sh = __int_as_float(sh_i);                                     \
    float m0 = fmaxf(v0, sh);                                            \
    float m1 = fmaxf(v1, v0);                                            \
    float m2 = fmaxf(v2, v1);                                            \
    float m3 = fmaxf(v3, v2);                                            \
    w0 = (w0 >> 1) | (__float_as_uint(v0 - m0) & 0x80000000u);           \
    w1 = (w1 >> 1) | (__float_as_uint(v1 - m1) & 0x80000000u);           \
    w2 = (w2 >> 1) | (__float_as_uint(v2 - m2) & 0x80000000u);           \
    w3 = (w3 >> 1) | (__float_as_uint(v3 - m3) & 0x80000000u);           \
    v0 = col.x + m0;                                                     \
    v1 = col.y + m1;                                                     \
    v2 = col.z + m2;                                                     \
    v3 = col.w + m3;                                                     \
  }

__global__ __launch_bounds__(512, 1) void k_dp(
    const float* __restrict__ lpT, const int* __restrict__ xlp,
    const int* __restrict__ ylp, float* __restrict__ dr_out,
    int* __restrict__ cum_ws, int* __restrict__ xt_ws)
{
  const int b = blockIdx.x;
  const int tid = threadIdx.x;
  const int lane = tid & 63;
  const int w = tid >> 6;                 // 0 = consumer, 1..7 = producers
  __shared__ __align__(16) float    ring[6 * 16 * 256];  // 96 KB, 6 slots
  __shared__ __align__(16) uint32_t bits[8192];          // 32 KB
  __shared__ __align__(16) uint32_t dur[TX_];            // 1 KB
  __shared__ __align__(16) uint32_t flags[64];
  __shared__ int      prog;

  const float4* gb4   = (const float4*)(lpT + (size_t)b * TY_ * TX_);
  const float4* ring4 = (const float4*)ring;

  const int ylen = ylp[b];
  const int nch  = ((ylen + 31) >> 5) << 1;   // even # of 16-row chunks, 32..64

  if (tid < 64) flags[tid] = 0u;
  if (tid == 0) prog = -1;
  __syncthreads();

  if (w == 0) {
    // ---------------- consumer: pure LDS + VALU DP (R23 exact) ----------------
    volatile int* vprog = &prog;
    POLL_PAIR(0);                          // chunks 0 and 1 staged
    float4 rrA[8], rrB[8];

    float v0 = (lane == 0) ? 0.0f : NEGF;
    float v1 = NEGF, v2 = NEGF, v3 = NEGF;
    uint32_t w0 = 0, w1 = 0, w2 = 0, w3 = 0;
    int sh_i = __float_as_int(NEGF);       // persistent; lane0 stays NEGF
    int slot = 0;

    ISSUE8(rrA, 0, 0);                     // group 0 (chunk 0, rows 0..7)

    for (int cp = 0; cp < nch; cp += 2) {
      if (cp + 2 < nch) POLL_PAIR(cp + 2); // flags cp+2 & cp+3
      const int s0 = slot;
      const int s1 = (s0 + 1 == 6) ? 0 : s0 + 1;
      const int s2 = (s1 + 1 == 6) ? 0 : s1 + 1;

      ISSUE8(rrB, s0, 1)                   // group 4k+1
      CONS8(rrA)                           // group 4k   (bits 0..7)
      ISSUE8(rrA, s1, 0)                   // group 4k+2
      CONS8(rrB)                           // group 4k+1 (bits 8..15)
      ISSUE8(rrB, s1, 1)                   // group 4k+3
      CONS8(rrA)                           // group 4k+2 (bits 16..23)
      if (cp + 2 < nch) { ISSUE8(rrA, s2, 0) }  // group 4k+4 (next iter)
      CONS8(rrB)                           // group 4k+3 (bits 24..31)

      *(uint4*)&bits[(cp >> 1) * 256 + 4 * lane] = make_uint4(w0, w1, w2, w3);
      w0 = w1 = w2 = w3 = 0;
      asm volatile("" ::: "memory");
      *vprog = cp + 1;
      slot = s2;
    }
  } else {
    // ---------------- producers: global -> reg -> LDS ring ----------------
    const int p = w - 1;                  // 0..6, handles chunks c ≡ p (mod 7)
    volatile int*      vprog = &prog;
    volatile uint32_t* vflag = flags;
    for (int c = p; c < nch; c += 7) {
      const int need = c - 6;             // slot tenant c-6 must be consumed
      while (*vprog < need) __builtin_amdgcn_s_sleep(8);
      asm volatile("" ::: "memory");
      const float4* src = gb4 + (size_t)(c * 16) * 64 + lane;
      float4 tmp[16];
#pragma unroll
      for (int r = 0; r < 16; ++r) tmp[r] = src[r * 64];
      float4* dst = (float4*)&ring[(c % 6) * 4096] + lane;
#pragma unroll
      for (int r = 0; r < 16; ++r) dst[r * 64] = tmp[r];
      asm volatile("s_waitcnt lgkmcnt(0)" ::: "memory");
      vflag[c] = 1u;
    }
  }

  __syncthreads();
  if (tid < TX_) dur[tid] = 0;
  __syncthreads();

  const int xlen = xlp[b];
  if (tid == 0) {
    int idx = xlen - 1;
    int t = ylen - 1;
    while (t >= 0) {
      if (idx == 0) { dur[0] = (uint32_t)(t + 1); break; }
      int ww = t >> 5, rrm = t & 31;
      uint32_t wd = bits[ww * 256 + idx];
      wd &= (rrm == 31) ? 0xffffffffu : ((1u << (rrm + 1)) - 1u);
      while (wd == 0 && ww > 0) { --ww; wd = bits[ww * 256 + idx]; }
      if (wd == 0) { dur[idx] = (uint32_t)(t + 1); break; }
      int bitpos = 31 - __builtin_clz(wd);
      int tp = (ww << 5) | bitpos;       // step where diag fires -> decrement
      dur[idx] = (uint32_t)(t - tp + 1); // first visit of idx -> plain store
      --idx;
      t = tp - 1;
    }
  }
  __syncthreads();

  if (w == 0) {
    // wave-wide inclusive scan of durations -> cum, dr, and t->x scatter map
    uint32_t d0 = dur[4 * lane], d1 = dur[4 * lane + 1];
    uint32_t d2 = dur[4 * lane + 2], d3 = dur[4 * lane + 3];
    uint32_t own = d0 + d1 + d2 + d3;
    uint32_t s = own;
#pragma unroll
    for (int off = 1; off < 64; off <<= 1) {
      uint32_t n = __shfl_up(s, off);
      if (lane >= off) s += n;
    }
    uint32_t base = s - own;
    uint32_t c0 = base + d0, c1 = c0 + d1, c2 = c1 + d2, c3 = c2 + d3;
    int x = 4 * lane;
    cum_ws[b * TX_ + x]     = (int)c0;
    cum_ws[b * TX_ + x + 1] = (int)c1;
    cum_ws[b * TX_ + x + 2] = (int)c2;
    cum_ws[b * TX_ + x + 3] = (int)c3;
    dr_out[b * TX_ + x]     = (float)d0;
    dr_out[b * TX_ + x + 1] = (float)d1;
    dr_out[b * TX_ + x + 2] = (float)d2;
    dr_out[b * TX_ + x + 3] = (float)d3;
    int* xt = xt_ws + b * TY_;
    for (uint32_t t = c0 - d0; t < c0; ++t) xt[t] = x;
    for (uint32_t t = c1 - d1; t < c1; ++t) xt[t] = x + 1;
    for (uint32_t t = c2 - d2; t < c2; ++t) xt[t] = x + 2;
    for (uint32_t t = c3 - d3; t < c3; ++t) xt[t] = x + 3;
  }
}

// ---------------------------------------------------------------------------
// Kernel C (fused epilogue): blocks [0,TX) write attn rows from cum;
// blocks [TX,TX+H) gather o_en_ex[b,h,t] = t<ylen ? en[b,h,xt[b,t]] : 0.
// ---------------------------------------------------------------------------
__global__ __launch_bounds__(256) void k_epi(
    const int* __restrict__ cum_ws, const int* __restrict__ xt_ws,
    const float* __restrict__ en, const int* __restrict__ ylp,
    float* __restrict__ attn, float* __restrict__ oen)
{
  const int b = blockIdx.y, bx = blockIdx.x, tid = threadIdx.x;
  __shared__ float row[TX_];
  if (bx < TX_) {
    const int x = bx;
    int hi = cum_ws[b * TX_ + x];
    int lo = (x > 0) ? cum_ws[b * TX_ + x - 1] : 0;
    int t0 = tid * 4;
    float4 v;
    v.x = (t0     >= lo && t0     < hi) ? 1.f : 0.f;
    v.y = (t0 + 1 >= lo && t0 + 1 < hi) ? 1.f : 0.f;
    v.z = (t0 + 2 >= lo && t0 + 2 < hi) ? 1.f : 0.f;
    v.w = (t0 + 3 >= lo && t0 + 3 < hi) ? 1.f : 0.f;
    *(float4*)&attn[((size_t)(b * TX_ + x)) * TY_ + t0] = v;
  } else {
    const int h = bx - TX_;
    row[tid] = en[((size_t)(b * H_ + h)) * TX_ + tid];
    __syncthreads();
    const int ylen = ylp[b];
    int t0 = tid * 4;
    int4 xi = *(const int4*)&xt_ws[b * TY_ + t0];
    float4 v;
    v.x = (t0     < ylen) ? row[xi.x & (TX_ - 1)] : 0.f;
    v.y = (t0 + 1 < ylen) ? row[xi.y & (TX_ - 1)] : 0.f;
    v.z = (t0 + 2 < ylen) ? row[xi.z & (TX_ - 1)] : 0.f;
    v.w = (t0 + 3 < ylen) ? row[xi.w & (TX_ - 1)] : 0.f;
    *(float4*)&oen[((size_t)(b * H_ + h)) * TY_ + t0] = v;
  }
}

extern "C" void kernel_launch(void* const* d_in, const int* in_sizes, int n_in,
                              void* d_out, int out_size, void* d_ws, size_t ws_size,
                              hipStream_t stream)
{
  const float* en = (const float*)d_in[0];
  const float* mu = (const float*)d_in[1];
  const float* ls = (const float*)d_in[2];
  const float* y  = (const float*)d_in[3];
  const int*   xl = (const int*)d_in[4];
  const int*   yl = (const int*)d_in[5];

  float* out  = (float*)d_out;
  float* oen  = out;             // [B,H,TY]
  float* logp = out + OFF_LOGP;  // [B,TX,TY]
  float* attn = out + OFF_ATTN;  // [B,TX,TY] (doubles as lpT scratch first)
  float* dr   = out + OFF_DR;    // [B,TX]

  int* cum = (int*)d_ws;               // B*TX ints
  int* xt  = cum + B_ * TX_;           // B*TY ints

  k_logp<<<dim3(TX_ / 4, TY_ / 256, B_), 256, 0, stream>>>(mu, ls, y, xl, yl, logp, attn);
  k_dp  <<<B_,                           512, 0, stream>>>(attn, xl, yl, dr, cum, xt);
  k_epi <<<dim3(TX_ + H_, B_),           256, 0, stream>>>(cum, xt, en, yl, attn, oen);
}

// Round 15
// 164.146 us; speedup vs baseline: 1.0768x; 1.0768x over previous
//
#include <hip/hip_runtime.h>
#include <cstdint>
#include <cmath>

#define B_ 4
#define H_ 256
#define C_ 80
#define TX_ 256
#define TY_ 1024
#define NEGF (-1e9f)

// output layout (floats): o_en_ex [B,H,TY] | logp [B,TX,TY] | attn [B,TX,TY] | dr [B,TX]
#define OFF_LOGP (B_*H_*TY_)
#define OFF_ATTN (OFF_LOGP + B_*TX_*TY_)
#define OFF_DR   (OFF_ATTN + B_*TX_*TY_)

// ---------------------------------------------------------------------------
// FINAL BUILD (R23 configuration, best verified: 163.6us total).
//
// Session accounting (all measured):
//   k_dp   ~76us  - serial Viterbi DP, latency-bound; 8 structural variants
//                   (skew, single-wave, barrier-PC, barrier-free-PC, strip/
//                   readlane backtrack, 2-bank pipeline, 2-consumer split,
//                   7-producer) converge to ~175cyc/step vs ~80 modeled.
//   k_logp ~15us  - measured via R24 duplicate-launch delta; at issue model.
//   k_epi   ~5us  - at model.
//   gaps   ~10us, harness floor ~50us - measured via R17 fused-vs-bench.
// ---------------------------------------------------------------------------

// ---------------------------------------------------------------------------
// Kernel A (R18 build): logp, 4 waves/SIMD, math BIT-IDENTICAL to reference
// staging order.
// ---------------------------------------------------------------------------
__global__ __launch_bounds__(256) void k_logp(
    const float* __restrict__ mu, const float* __restrict__ ls,
    const float* __restrict__ y, const int* __restrict__ xlp,
    const int* __restrict__ ylp, float* __restrict__ logp_out,
    float* __restrict__ lpT)
{
  const int b  = blockIdx.z;
  const int tq = blockIdx.y;              // t-quarter: rows tq*256 .. tq*256+255
  const int x0 = blockIdx.x * 4;
  const int tid = threadIdx.x;
  const int lane = tid & 63;
  const int xi = tid >> 6;                // wave id == x-column index

  __shared__ double2 s_wm[4][C_];         // (w, -2*w*mu) packed -> ds_read_b128
  __shared__ double  s_wm2[4][C_];
  __shared__ double  s_lsv[4][C_];
  __shared__ double  s_K[4];
  __shared__ double  s_t0[4];
  __shared__ float   tile[256][4];        // [t_local][x] transpose staging

  for (int i = tid; i < 4 * C_; i += 256) {
    int xj = i / C_, c = i - xj * C_;
    double m = (double)mu[(b * C_ + c) * TX_ + x0 + xj];
    double l = (double)ls[(b * C_ + c) * TX_ + x0 + xj];
    double w = exp(-2.0 * l);
    s_wm[xj][c]  = make_double2(w, -2.0 * w * m);
    s_wm2[xj][c] = w * m * m;
    s_lsv[xj][c] = l;
  }
  __syncthreads();
  {
    int cc = lane;
    double kp = (cc < C_) ? s_wm2[xi][cc] : 0.0;
    double tp = (cc < C_) ? s_lsv[xi][cc] : 0.0;
    if (cc + 64 < C_) { kp += s_wm2[xi][cc + 64]; tp += s_lsv[xi][cc + 64]; }
#pragma unroll
    for (int off = 32; off; off >>= 1) {
      kp += __shfl_down(kp, off);
      tp += __shfl_down(tp, off);
    }
    if (cc == 0) { s_K[xi] = kp; s_t0[xi] = -0.5 * (tp * (1.0 / C_)); }
  }
  __syncthreads();

  double acc[4];
#pragma unroll
  for (int k = 0; k < 4; ++k) acc[k] = 0.0;

  const float4* yp = (const float4*)(y + (size_t)b * C_ * TY_ + tq * 256) + lane;
#pragma unroll 4
  for (int c = 0; c < C_; ++c) {
    float4 yv = yp[c * (TY_ / 4)];
    double y0 = yv.x, y1 = yv.y, y2 = yv.z, y3 = yv.w;
    double2 wm = s_wm[xi][c];
    double w = wm.x, m1 = wm.y;
    double u0 = fma(w, y0, m1), u1 = fma(w, y1, m1);
    double u2 = fma(w, y2, m1), u3 = fma(w, y3, m1);
    acc[0] = fma(u0, y0, acc[0]);
    acc[1] = fma(u1, y1, acc[1]);
    acc[2] = fma(u2, y2, acc[2]);
    acc[3] = fma(u3, y3, acc[3]);
  }

  const int xlen = xlp[b], ylen = ylp[b];
  const int x  = x0 + xi;
  const int t0 = tq * 256 + lane * 4;
  {
    double c0 = s_t0[xi], K = s_K[xi];
    float r[4];
#pragma unroll
    for (int k = 0; k < 4; ++k)
      r[k] = (float)((acc[k] + K) * (-0.5 / C_) + c0);
    *(float4*)&logp_out[((size_t)(b * TX_ + x)) * TY_ + t0] =
        make_float4(r[0], r[1], r[2], r[3]);
    bool xm = x < xlen;
#pragma unroll
    for (int k = 0; k < 4; ++k)
      tile[lane * 4 + k][xi] = (xm && (t0 + k) < ylen) ? r[k] : NEGF;
  }
  __syncthreads();

  float* dst = lpT + (size_t)b * TY_ * TX_ + x0;
  const float4* tp = (const float4*)tile;
  *(float4*)&dst[(size_t)(tq * 256 + tid) * TX_] = tp[tid];
}

// ---------------------------------------------------------------------------
// Kernel B (R23 build): barrier-free producer-consumer Viterbi DP.
// 1 consumer wave (two-bank explicit register pipeline) + 3 producer waves
// staging 16-row chunks into a 6-slot LDS ring; LDS-flag sync, no barriers
// in the main loop.  R16 backtrack.
// ---------------------------------------------------------------------------
#define POLL_PAIR(i)                                                     \
  { const volatile unsigned long long* vp2 =                             \
        (const volatile unsigned long long*)&flags[i];                   \
    for (;;) { unsigned long long fv = *vp2;                             \
      if ((unsigned)fv && (fv >> 32)) break;                             \
      __builtin_amdgcn_s_sleep(1); }                                     \
    asm volatile("" ::: "memory"); }

#define ISSUE8(BANK, SC, HALF)                                           \
  _Pragma("unroll")                                                      \
  for (int i = 0; i < 8; ++i)                                            \
    BANK[i] = ring4[(SC) * 1024 + ((HALF) * 8 + i) * 64 + lane];

#define CONS8(BANK)                                                      \
  _Pragma("unroll")                                                      \
  for (int u = 0; u < 8; ++u) {                                          \
    float4 col = BANK[u];                                                \
    sh_i = __builtin_amdgcn_update_dpp(sh_i, __float_as_int(v3),         \
                                       0x138, 0xf, 0xf, false);          \
    float sh = __int_as_float(sh_i);                                     \
    float m0 = fmaxf(v0, sh);                                            \
    float m1 = fmaxf(v1, v0);                                            \
    float m2 = fmaxf(v2, v1);                                            \
    float m3 = fmaxf(v3, v2);                                            \
    w0 = (w0 >> 1) | (__float_as_uint(v0 - m0) & 0x80000000u);           \
    w1 = (w1 >> 1) | (__float_as_uint(v1 - m1) & 0x80000000u);           \
    w2 = (w2 >> 1) | (__float_as_uint(v2 - m2) & 0x80000000u);           \
    w3 = (w3 >> 1) | (__float_as_uint(v3 - m3) & 0x80000000u);           \
    v0 = col.x + m0;                                                     \
    v1 = col.y + m1;                                                     \
    v2 = col.z + m2;                                                     \
    v3 = col.w + m3;                                                     \
  }

__global__ __launch_bounds__(256, 1) void k_dp(
    const float* __restrict__ lpT, const int* __restrict__ xlp,
    const int* __restrict__ ylp, float* __restrict__ dr_out,
    int* __restrict__ cum_ws, int* __restrict__ xt_ws)
{
  const int b = blockIdx.x;
  const int tid = threadIdx.x;
  const int lane = tid & 63;
  const int w = tid >> 6;                 // 0 = consumer, 1..3 = producers
  __shared__ __align__(16) float    ring[6 * 16 * 256];  // 96 KB, 6 slots
  __shared__ __align__(16) uint32_t bits[8192];          // 32 KB
  __shared__ __align__(16) uint32_t dur[TX_];            // 1 KB
  __shared__ __align__(16) uint32_t flags[64];
  __shared__ int      prog;

  const float4* gb4   = (const float4*)(lpT + (size_t)b * TY_ * TX_);
  const float4* ring4 = (const float4*)ring;

  const int ylen = ylp[b];
  const int nch  = ((ylen + 31) >> 5) << 1;   // even # of 16-row chunks, 32..64

  if (tid < 64) flags[tid] = 0u;
  if (tid == 0) prog = -1;
  __syncthreads();

  if (w == 0) {
    // ---------------- consumer: pure LDS + VALU DP ----------------
    volatile int* vprog = &prog;
    POLL_PAIR(0);                          // chunks 0 and 1 staged
    float4 rrA[8], rrB[8];

    float v0 = (lane == 0) ? 0.0f : NEGF;
    float v1 = NEGF, v2 = NEGF, v3 = NEGF;
    uint32_t w0 = 0, w1 = 0, w2 = 0, w3 = 0;
    int sh_i = __float_as_int(NEGF);       // persistent; lane0 stays NEGF
    int slot = 0;

    ISSUE8(rrA, 0, 0);                     // group 0 (chunk 0, rows 0..7)

    for (int cp = 0; cp < nch; cp += 2) {
      if (cp + 2 < nch) POLL_PAIR(cp + 2); // flags cp+2 & cp+3
      const int s0 = slot;
      const int s1 = (s0 + 1 == 6) ? 0 : s0 + 1;
      const int s2 = (s1 + 1 == 6) ? 0 : s1 + 1;

      ISSUE8(rrB, s0, 1)                   // group 4k+1
      CONS8(rrA)                           // group 4k   (bits 0..7)
      ISSUE8(rrA, s1, 0)                   // group 4k+2
      CONS8(rrB)                           // group 4k+1 (bits 8..15)
      ISSUE8(rrB, s1, 1)                   // group 4k+3
      CONS8(rrA)                           // group 4k+2 (bits 16..23)
      if (cp + 2 < nch) { ISSUE8(rrA, s2, 0) }  // group 4k+4 (next iter)
      CONS8(rrB)                           // group 4k+3 (bits 24..31)

      *(uint4*)&bits[(cp >> 1) * 256 + 4 * lane] = make_uint4(w0, w1, w2, w3);
      w0 = w1 = w2 = w3 = 0;
      asm volatile("" ::: "memory");
      *vprog = cp + 1;
      slot = s2;
    }
  } else {
    // ---------------- producers: global -> reg -> LDS ring ----------------
    const int p = w - 1;                  // 0..2, handles chunks c ≡ p (mod 3)
    volatile int*      vprog = &prog;
    volatile uint32_t* vflag = flags;
    for (int c = p; c < nch; c += 3) {
      const int need = c - 6;             // slot tenant c-6 must be consumed
      while (*vprog < need) __builtin_amdgcn_s_sleep(8);
      asm volatile("" ::: "memory");
      const float4* src = gb4 + (size_t)(c * 16) * 64 + lane;
      float4 tmp[16];
#pragma unroll
      for (int r = 0; r < 16; ++r) tmp[r] = src[r * 64];
      float4* dst = (float4*)&ring[(c % 6) * 4096] + lane;
#pragma unroll
      for (int r = 0; r < 16; ++r) dst[r * 64] = tmp[r];
      asm volatile("s_waitcnt lgkmcnt(0)" ::: "memory");
      vflag[c] = 1u;
    }
  }

  __syncthreads();
  dur[tid] = 0;
  __syncthreads();

  const int xlen = xlp[b];
  if (tid == 0) {
    int idx = xlen - 1;
    int t = ylen - 1;
    while (t >= 0) {
      if (idx == 0) { dur[0] = (uint32_t)(t + 1); break; }
      int ww = t >> 5, rrm = t & 31;
      uint32_t wd = bits[ww * 256 + idx];
      wd &= (rrm == 31) ? 0xffffffffu : ((1u << (rrm + 1)) - 1u);
      while (wd == 0 && ww > 0) { --ww; wd = bits[ww * 256 + idx]; }
      if (wd == 0) { dur[idx] = (uint32_t)(t + 1); break; }
      int bitpos = 31 - __builtin_clz(wd);
      int tp = (ww << 5) | bitpos;       // step where diag fires -> decrement
      dur[idx] = (uint32_t)(t - tp + 1); // first visit of idx -> plain store
      --idx;
      t = tp - 1;
    }
  }
  __syncthreads();

  if (w == 0) {
    // wave-wide inclusive scan of durations -> cum, dr, and t->x scatter map
    uint32_t d0 = dur[4 * lane], d1 = dur[4 * lane + 1];
    uint32_t d2 = dur[4 * lane + 2], d3 = dur[4 * lane + 3];
    uint32_t own = d0 + d1 + d2 + d3;
    uint32_t s = own;
#pragma unroll
    for (int off = 1; off < 64; off <<= 1) {
      uint32_t n = __shfl_up(s, off);
      if (lane >= off) s += n;
    }
    uint32_t base = s - own;
    uint32_t c0 = base + d0, c1 = c0 + d1, c2 = c1 + d2, c3 = c2 + d3;
    int x = 4 * lane;
    cum_ws[b * TX_ + x]     = (int)c0;
    cum_ws[b * TX_ + x + 1] = (int)c1;
    cum_ws[b * TX_ + x + 2] = (int)c2;
    cum_ws[b * TX_ + x + 3] = (int)c3;
    dr_out[b * TX_ + x]     = (float)d0;
    dr_out[b * TX_ + x + 1] = (float)d1;
    dr_out[b * TX_ + x + 2] = (float)d2;
    dr_out[b * TX_ + x + 3] = (float)d3;
    int* xt = xt_ws + b * TY_;
    for (uint32_t t = c0 - d0; t < c0; ++t) xt[t] = x;
    for (uint32_t t = c1 - d1; t < c1; ++t) xt[t] = x + 1;
    for (uint32_t t = c2 - d2; t < c2; ++t) xt[t] = x + 2;
    for (uint32_t t = c3 - d3; t < c3; ++t) xt[t] = x + 3;
  }
}

// ---------------------------------------------------------------------------
// Kernel C (fused epilogue): blocks [0,TX) write attn rows from cum;
// blocks [TX,TX+H) gather o_en_ex[b,h,t] = t<ylen ? en[b,h,xt[b,t]] : 0.
// ---------------------------------------------------------------------------
__global__ __launch_bounds__(256) void k_epi(
    const int* __restrict__ cum_ws, const int* __restrict__ xt_ws,
    const float* __restrict__ en, const int* __restrict__ ylp,
    float* __restrict__ attn, float* __restrict__ oen)
{
  const int b = blockIdx.y, bx = blockIdx.x, tid = threadIdx.x;
  __shared__ float row[TX_];
  if (bx < TX_) {
    const int x = bx;
    int hi = cum_ws[b * TX_ + x];
    int lo = (x > 0) ? cum_ws[b * TX_ + x - 1] : 0;
    int t0 = tid * 4;
    float4 v;
    v.x = (t0     >= lo && t0     < hi) ? 1.f : 0.f;
    v.y = (t0 + 1 >= lo && t0 + 1 < hi) ? 1.f : 0.f;
    v.z = (t0 + 2 >= lo && t0 + 2 < hi) ? 1.f : 0.f;
    v.w = (t0 + 3 >= lo && t0 + 3 < hi) ? 1.f : 0.f;
    *(float4*)&attn[((size_t)(b * TX_ + x)) * TY_ + t0] = v;
  } else {
    const int h = bx - TX_;
    row[tid] = en[((size_t)(b * H_ + h)) * TX_ + tid];
    __syncthreads();
    const int ylen = ylp[b];
    int t0 = tid * 4;
    int4 xi = *(const int4*)&xt_ws[b * TY_ + t0];
    float4 v;
    v.x = (t0     < ylen) ? row[xi.x & (TX_ - 1)] : 0.f;
    v.y = (t0 + 1 < ylen) ? row[xi.y & (TX_ - 1)] : 0.f;
    v.z = (t0 + 2 < ylen) ? row[xi.z & (TX_ - 1)] : 0.f;
    v.w = (t0 + 3 < ylen) ? row[xi.w & (TX_ - 1)] : 0.f;
    *(float4*)&oen[((size_t)(b * H_ + h)) * TY_ + t0] = v;
  }
}

extern "C" void kernel_launch(void* const* d_in, const int* in_sizes, int n_in,
                              void* d_out, int out_size, void* d_ws, size_t ws_size,
                              hipStream_t stream)
{
  const float* en = (const float*)d_in[0];
  const float* mu = (const float*)d_in[1];
  const float* ls = (const float*)d_in[2];
  const float* y  = (const float*)d_in[3];
  const int*   xl = (const int*)d_in[4];
  const int*   yl = (const int*)d_in[5];

  float* out  = (float*)d_out;
  float* oen  = out;             // [B,H,TY]
  float* logp = out + OFF_LOGP;  // [B,TX,TY]
  float* attn = out + OFF_ATTN;  // [B,TX,TY] (doubles as lpT scratch first)
  float* dr   = out + OFF_DR;    // [B,TX]

  int* cum = (int*)d_ws;               // B*TX ints
  int* xt  = cum + B_ * TX_;           // B*TY ints

  k_logp<<<dim3(TX_ / 4, TY_ / 256, B_), 256, 0, stream>>>(mu, ls, y, xl, yl, logp, attn);
  k_dp  <<<B_,                           256, 0, stream>>>(attn, xl, yl, dr, cum, xt);
  k_epi <<<dim3(TX_ + H_, B_),           256, 0, stream>>>(cum, xt, en, yl, attn, oen);
}